// Round 13
// baseline (211.654 us; speedup 1.0000x reference)
//
#include <hip/hip_runtime.h>
#include <hip/hip_fp16.h>
#include <stdint.h>

// Problem constants (B,C_IN,L fixed by the reference)
#define BB    4
#define CIN   512
#define CRED  256
#define LL    16384
#define NBLK  256      // L / 64
#define WELEM 131072   // elements per weight matrix

typedef _Float16 half8 __attribute__((ext_vector_type(8)));
typedef float    f32x4 __attribute__((ext_vector_type(4)));

#define SWZ(r) (((r)&7)<<4)

// ---------------- workspace layout (elements of _Float16) -----------------
// [0, 524288)  : weights, FRAGMENT-MAJOR
//   p<3 (K=512): addr = p*WELEM + m16*8192 + ks*512 + l4*128 + l15*8 + e
//   p=3 (K=256): addr = 3*WELEM + m16*4096 + ks*512 + l4*128 + l15*8 + e
// XFH : X^T fragment-major for the CURRENT batch-half (512 tiles x 32768 el)
//       el = tl*32768 + ks*2048 + l4*512 + pos*8 + e   (ch = ks*32+l4*8+e)
// QB  : Q tiles  [t 1024][pos 64][ch 256]   (t = b*256+n)
// KB  : K tiles  same
// VB  : V tiles  [t 1024][ch 256][pos 64]
#define XFH     524288
#define QB      (XFH + 16777216)
#define KB      (QB  + 16777216)
#define VB      (KB  + 16777216)
#define WS_NEED ((size_t)(VB + 16777216) * 2)   // 135.27 MB — proven in R9/R10

// ---- fragment-major weight conversion (main path) ----
__global__ void convert_weights_fm(const float* __restrict__ Wq,
                                   const float* __restrict__ Wk,
                                   const float* __restrict__ Wv,
                                   const float* __restrict__ Wo,
                                   _Float16* __restrict__ dst) {
    int i = blockIdx.x * blockDim.x + threadIdx.x;
    int p = i >> 17;
    int e17 = i & (WELEM - 1);
    const float* src = (p == 0) ? Wq : (p == 1) ? Wk : (p == 2) ? Wv : Wo;
    const int Kd = (p < 3) ? 512 : 256;
    const int sh = (p < 3) ? 13 : 12;
    const int m16 = e17 >> sh;
    const int rem = e17 & ((1 << sh) - 1);
    const int ks  = rem >> 9;
    const int l4  = (rem >> 7) & 3;
    const int l15 = (rem >> 3) & 15;
    const int ee  = rem & 7;
    const int r = m16 * 16 + l15;
    const int k = ks * 32 + l4 * 8 + ee;
    dst[(size_t)p * WELEM + e17] = (_Float16)src[(size_t)r * Kd + k];
}

// ---- row-major conversion (fallback path only) ----
__global__ void convert_weights_rm(const float* __restrict__ Wq,
                                   const float* __restrict__ Wk,
                                   const float* __restrict__ Wv,
                                   const float* __restrict__ Wo,
                                   _Float16* __restrict__ dst) {
    int i = blockIdx.x * blockDim.x + threadIdx.x;
    int m = i >> 17;
    int e = i & (WELEM - 1);
    const float* src = (m == 0) ? Wq : (m == 1) ? Wk : (m == 2) ? Wv : Wo;
    dst[(size_t)m * WELEM + e] = (_Float16)src[e];
}

// ============ K1: x1 f32 -> XF fp16 fragment-major (one batch-half) ========
// 2048 blocks: 512 local tiles x 4 ch-chunks. Pure streaming, 16 KB LDS.
__global__ __launch_bounds__(256, 4)
void x_transpose(const float* __restrict__ x1, _Float16* __restrict__ xfb,
                 int b0) {
    __shared__ char lds[16384];            // [64 pos][128 ch] fp16, rows 256 B
    const int tid = threadIdx.x;
    const int blk = blockIdx.x;
    const int tl  = blk >> 2;              // local tile 0..511
    const int cc  = blk & 3;               // 128-ch chunk
    const int b   = b0 + (tl >> 8), n = tl & 255;
    const int jx  = tid & 15;              // pos quad
    const int rg  = tid >> 4;              // ch octet 0..15

    const float* xp = x1 + ((size_t)b * CIN + cc * 128 + 8 * rg) * LL + n * 64 + 4 * jx;
    f32x4 r[8];
    #pragma unroll
    for (int k = 0; k < 8; ++k)
        r[k] = *(const f32x4*)(xp + (size_t)k * LL);
    asm volatile("" ::: "memory");         // burst all 8 loads before converts
    #pragma unroll
    for (int u = 0; u < 4; ++u) {
        const int j = 4 * jx + u;
        union { _Float16 h[8]; half8 v; } pk;
        #pragma unroll
        for (int k = 0; k < 8; ++k) pk.h[k] = (_Float16)r[k][u];
        *(half8*)(lds + j * 256 + ((16 * rg) ^ SWZ(j))) = pk.v;
    }
    __syncthreads();
    // dump fragment-major; rr = ks within chunk; fully coalesced writes
    _Float16* dst = xfb + (size_t)tl * 32768 + cc * 8192;
    const int l4d = tid >> 6, jd = tid & 63;
    #pragma unroll
    for (int rr = 0; rr < 4; ++rr) {
        half8 v = *(const half8*)(lds + jd * 256 + ((rr * 64 + l4d * 16) ^ SWZ(jd)));
        *(half8*)(dst + rr * 2048 + tid * 8) = v;
    }
}

// ====== K2: QKV v5 — ZERO LDS, ZERO barriers, direct global fragments ======
// Grid 1536 (3 p x 512 local tiles), 256 thr / 4 waves, LB(256,3) -> 12
// waves/CU, 170 reg cap (irreducible ~110 -> compiler self-pipelines the
// unrolled loop). Exactly attn_out's structural regime.
__global__ __launch_bounds__(256, 3)
void qkv_v5(const _Float16* __restrict__ W, const _Float16* __restrict__ xfb,
            const float* __restrict__ bq, const float* __restrict__ bk,
            const float* __restrict__ bv, _Float16* __restrict__ ws, int b0) {
    const int tid = threadIdx.x;
    const int wid = tid >> 6;
    const int l15 = tid & 15;
    const int l4  = (tid & 63) >> 4;
    const int p   = blockIdx.x >> 9;       // matrix 0..2
    const int tl  = blockIdx.x & 511;      // local tile
    const size_t tg = (size_t)b0 * 256 + tl;   // global tile (b*256+n)

    const _Float16* xf  = xfb + (size_t)tl * 32768;
    const _Float16* wf0 = W + (size_t)p * WELEM + (size_t)(wid * 4) * 8192
                        + l4 * 128 + l15 * 8;

    f32x4 acc[4][4];
    #pragma unroll
    for (int mt = 0; mt < 4; ++mt)
        #pragma unroll
        for (int q = 0; q < 4; ++q) acc[mt][q] = (f32x4){0.f, 0.f, 0.f, 0.f};

    #pragma unroll
    for (int ks = 0; ks < 16; ++ks) {
        half8 xfr[4], wfr[4];
        #pragma unroll
        for (int nt = 0; nt < 4; ++nt)
            xfr[nt] = *(const half8*)(xf + ks * 2048 + l4 * 512 + (nt * 16 + l15) * 8);
        #pragma unroll
        for (int mt = 0; mt < 4; ++mt)
            wfr[mt] = *(const half8*)(wf0 + mt * 8192 + ks * 512);
        #pragma unroll
        for (int mt = 0; mt < 4; ++mt)
            #pragma unroll
            for (int nt = 0; nt < 4; ++nt)
                acc[mt][nt] = __builtin_amdgcn_mfma_f32_16x16x32_f16(
                    wfr[mt], xfr[nt], acc[mt][nt], 0, 0, 0);
    }

    const float* bias = (p == 0) ? bq : (p == 1) ? bk : bv;
    if (p < 2) {
        _Float16* dst = ws + (p ? KB : QB) + tg * 16384;   // [pos][ch]
        #pragma unroll
        for (int mt = 0; mt < 4; ++mt) {
            const int c0 = wid * 64 + mt * 16 + l4 * 4;
            f32x4 b4 = *(const f32x4*)(bias + c0);
            #pragma unroll
            for (int nt = 0; nt < 4; ++nt) {
                const int pos = nt * 16 + l15;
                union { _Float16 h[4]; uint64_t q; } pk;
                #pragma unroll
                for (int ri = 0; ri < 4; ++ri)
                    pk.h[ri] = (_Float16)(acc[mt][nt][ri] + b4[ri]);
                *(uint64_t*)(dst + (size_t)pos * CRED + c0) = pk.q;
            }
        }
    } else {
        _Float16* vd = ws + VB + tg * 16384;               // [ch][pos 64]
        #pragma unroll
        for (int mt = 0; mt < 4; ++mt) {
            const int c0 = wid * 64 + mt * 16 + l4 * 4;
            f32x4 b4 = *(const f32x4*)(bias + c0);
            #pragma unroll
            for (int nt = 0; nt < 4; ++nt) {
                const int pos = nt * 16 + l15;
                #pragma unroll
                for (int ri = 0; ri < 4; ++ri)
                    vd[(size_t)(c0 + ri) * 64 + pos] =
                        (_Float16)(acc[mt][nt][ri] + b4[ri]);
            }
        }
    }
}

// ================ K3: attention + output projection (proven ~33 us) ========
#define BH_OFF 0
#define BP_OFF 32768
#define LDS_B  40960

__global__ __launch_bounds__(256, 3)
void attn_out(const float* __restrict__ mask, const _Float16* __restrict__ ws,
              const float* __restrict__ bo, float* __restrict__ out) {
    extern __shared__ char lds[];
    const int tid = threadIdx.x;
    const int wid = tid >> 6;
    const int l15 = tid & 15;
    const int l4  = (tid & 63) >> 4;
    const int t   = blockIdx.x;
    const int b   = t >> 8, n = t & 255;

    const _Float16* qt = ws + QB + (size_t)t * 16384;   // [pos][ch]
    const _Float16* kt = ws + KB + (size_t)t * 16384;
    const _Float16* vt = ws + VB + (size_t)t * 16384;   // [ch][pos]
    const _Float16* WoF = ws + 3 * (size_t)WELEM;       // fragment-major

    // -------- S = (Q^T K)*scale + in-register masked softmax -> P ---------
    {
        const int i0 = wid * 16;
        f32x4 sa[4];
        #pragma unroll
        for (int jt = 0; jt < 4; ++jt) sa[jt] = (f32x4){0.f, 0.f, 0.f, 0.f};
        #pragma unroll
        for (int ks = 0; ks < 8; ++ks) {
            half8 qa = *(const half8*)(qt + (size_t)(i0 + l15) * CRED + ks * 32 + l4 * 8);
            #pragma unroll
            for (int jt = 0; jt < 4; ++jt) {
                half8 kf = *(const half8*)(kt + (size_t)(jt * 16 + l15) * CRED + ks * 32 + l4 * 8);
                sa[jt] = __builtin_amdgcn_mfma_f32_16x16x32_f16(qa, kf, sa[jt], 0, 0, 0);
            }
        }
        float msk[4];
        #pragma unroll
        for (int jt = 0; jt < 4; ++jt)
            msk[jt] = mask[(size_t)b * LL + n * 64 + jt * 16 + l15];
        #pragma unroll
        for (int ri = 0; ri < 4; ++ri) {
            float v[4];
            #pragma unroll
            for (int jt = 0; jt < 4; ++jt)
                v[jt] = (msk[jt] == 0.f) ? -1e30f : sa[jt][ri] * 0.0625f;
            float mx = fmaxf(fmaxf(v[0], v[1]), fmaxf(v[2], v[3]));
            mx = fmaxf(mx, __shfl_xor(mx, 1));
            mx = fmaxf(mx, __shfl_xor(mx, 2));
            mx = fmaxf(mx, __shfl_xor(mx, 4));
            mx = fmaxf(mx, __shfl_xor(mx, 8));
            float e[4], sum = 0.f;
            #pragma unroll
            for (int jt = 0; jt < 4; ++jt) { e[jt] = __expf(v[jt] - mx); sum += e[jt]; }
            sum += __shfl_xor(sum, 1);
            sum += __shfl_xor(sum, 2);
            sum += __shfl_xor(sum, 4);
            sum += __shfl_xor(sum, 8);
            const float inv = 1.f / sum;
            const int i = i0 + l4 * 4 + ri;
            #pragma unroll
            for (int jt = 0; jt < 4; ++jt) {
                const int j = jt * 16 + l15;
                *(_Float16*)(lds + BP_OFF + i * 128 + ((2 * j) ^ SWZ(i))) =
                    (_Float16)(e[jt] * inv);
            }
        }
    }
    __syncthreads();   // P ready

    // -------- H = relu(V @ P^T) -------------------------------------------
    {
        const int cb = wid * 64;
        f32x4 pv[4][4];
        #pragma unroll
        for (int m = 0; m < 4; ++m)
            #pragma unroll
            for (int q = 0; q < 4; ++q) pv[m][q] = (f32x4){0.f, 0.f, 0.f, 0.f};
        #pragma unroll
        for (int ks = 0; ks < 2; ++ks) {
            const int kb = ks * 64 + l4 * 16;
            half8 pb[4];
            #pragma unroll
            for (int nt = 0; nt < 4; ++nt) {
                const int i = nt * 16 + l15;
                pb[nt] = *(const half8*)(lds + BP_OFF + i * 128 + (kb ^ SWZ(i)));
            }
            #pragma unroll
            for (int mt = 0; mt < 4; ++mt) {
                half8 va = *(const half8*)(vt + (size_t)(cb + mt * 16 + l15) * 64 + ks * 32 + l4 * 8);
                #pragma unroll
                for (int nt = 0; nt < 4; ++nt)
                    pv[mt][nt] = __builtin_amdgcn_mfma_f32_16x16x32_f16(va, pb[nt], pv[mt][nt], 0, 0, 0);
            }
        }
        #pragma unroll
        for (int mt = 0; mt < 4; ++mt) {
            const int c0 = cb + mt * 16 + l4 * 4;
            #pragma unroll
            for (int nt = 0; nt < 4; ++nt) {
                const int j = nt * 16 + l15;
                union { _Float16 h[4]; uint64_t q; } hp;
                #pragma unroll
                for (int ri = 0; ri < 4; ++ri)
                    hp.h[ri] = (_Float16)fmaxf(pv[mt][nt][ri], 0.f);
                *(uint64_t*)(lds + BH_OFF + j * 512 + ((2 * c0) ^ SWZ(j))) = hp.q;
            }
        }
    }
    __syncthreads();   // H ready

    // -------- Out = Wo @ H + bo  (Wo fragment-major) ----------------------
    #pragma unroll
    for (int op = 0; op < 2; ++op) {
        const int mbo = wid * 128 + op * 64;
        f32x4 oa[4][4];
        #pragma unroll
        for (int m = 0; m < 4; ++m)
            #pragma unroll
            for (int q = 0; q < 4; ++q) oa[m][q] = (f32x4){0.f, 0.f, 0.f, 0.f};
        const _Float16* wof = WoF + (size_t)(wid * 8 + op * 4) * 4096 + l4 * 128 + l15 * 8;
        #pragma unroll 4
        for (int ks = 0; ks < 8; ++ks) {
            const int kb = ks * 64 + l4 * 16;
            half8 hb[4];
            #pragma unroll
            for (int nt = 0; nt < 4; ++nt) {
                const int i = nt * 16 + l15;
                hb[nt] = *(const half8*)(lds + BH_OFF + i * 512 + (kb ^ SWZ(i)));
            }
            #pragma unroll
            for (int mt = 0; mt < 4; ++mt) {
                half8 wa = *(const half8*)(wof + mt * 4096 + ks * 512);
                #pragma unroll
                for (int nt = 0; nt < 4; ++nt)
                    oa[mt][nt] = __builtin_amdgcn_mfma_f32_16x16x32_f16(wa, hb[nt], oa[mt][nt], 0, 0, 0);
            }
        }
        #pragma unroll
        for (int mt = 0; mt < 4; ++mt) {
            const int o0 = mbo + mt * 16 + l4 * 4;
            f32x4 bov = *(const f32x4*)(bo + o0);
            #pragma unroll
            for (int ri = 0; ri < 4; ++ri) {
                float* orow = out + ((size_t)b * CIN + (o0 + ri)) * LL + n * 64;
                #pragma unroll
                for (int nt = 0; nt < 4; ++nt)
                    orow[nt * 16 + l15] = oa[mt][nt][ri] + bov[ri];
            }
        }
    }
}

// ================= Fallback: R5 fused kernel (verified, 168 us) ============
#define XT_OFF 0
#define Q_OFF  0
#define K_OFF  32768
#define V_OFF  32768
#define H_OFF  0
#define P_OFF  65536
#define MSK_OFF 73728
#define LDS_BYTES 73984

__global__ __launch_bounds__(256, 2)
void att_fused(const float* __restrict__ x1, const float* __restrict__ mask,
               const _Float16* __restrict__ W,
               const float* __restrict__ bq, const float* __restrict__ bk,
               const float* __restrict__ bv, const float* __restrict__ bo,
               float* __restrict__ out) {
    extern __shared__ char lds[];
    const int tid  = threadIdx.x;
    const int wid  = tid >> 6;
    const int lane = tid & 63;
    const int l15  = lane & 15;
    const int l4   = lane >> 4;
    const int blk  = blockIdx.x;
    const int b    = blk >> 8;
    const int n    = blk & 255;

    const _Float16* Wq = W;
    const _Float16* Wk = W + WELEM;
    const _Float16* Wv = W + 2 * WELEM;
    const _Float16* Wo = W + 3 * WELEM;

    {
        const int jx = tid & 15;
        const int rb = tid >> 4;
        const float* xbase = x1 + ((size_t)b * CIN + 2 * rb) * LL + n * 64 + 4 * jx;
        #pragma unroll
        for (int i = 0; i < 16; ++i) {
            f32x4 a = *(const f32x4*)(xbase + (size_t)(32 * i) * LL);
            f32x4 c = *(const f32x4*)(xbase + (size_t)(32 * i + 1) * LL);
            const int col = 4 * rb + 64 * i;
            #pragma unroll
            for (int u = 0; u < 4; ++u) {
                union { _Float16 h[2]; uint32_t w; } p;
                p.h[0] = (_Float16)a[u];
                p.h[1] = (_Float16)c[u];
                const int j = 4 * jx + u;
                *(uint32_t*)(lds + XT_OFF + j * 1024 + (col ^ SWZ(j))) = p.w;
            }
        }
        if (tid < 64)
            *(float*)(lds + MSK_OFF + tid * 4) = mask[(size_t)b * LL + n * 64 + tid];
    }
    __syncthreads();

    uint64_t qh[4][4], kh[4][4], vh[4][4];
    #pragma unroll
    for (int pass = 0; pass < 4; ++pass) {
        f32x4 aQ[4], aK[4], aV[4];
        #pragma unroll
        for (int q = 0; q < 4; ++q) {
            aQ[q] = (f32x4){0.f, 0.f, 0.f, 0.f};
            aK[q] = (f32x4){0.f, 0.f, 0.f, 0.f};
            aV[q] = (f32x4){0.f, 0.f, 0.f, 0.f};
        }
        const int mrow = wid * 64 + pass * 16 + l15;
        const _Float16* wqp = Wq + (size_t)mrow * CIN + l4 * 8;
        const _Float16* wkp = Wk + (size_t)mrow * CIN + l4 * 8;
        const _Float16* wvp = Wv + (size_t)mrow * CIN + l4 * 8;
        #pragma unroll 4
        for (int ks = 0; ks < 16; ++ks) {
            const int kb = ks * 64 + l4 * 16;
            half8 xb[4];
            #pragma unroll
            for (int nt = 0; nt < 4; ++nt) {
                const int j = nt * 16 + l15;
                xb[nt] = *(const half8*)(lds + XT_OFF + j * 1024 + (kb ^ SWZ(j)));
            }
            half8 aq = *(const half8*)(wqp + ks * 32);
            half8 ak = *(const half8*)(wkp + ks * 32);
            half8 av = *(const half8*)(wvp + ks * 32);
            #pragma unroll
            for (int nt = 0; nt < 4; ++nt) {
                aQ[nt] = __builtin_amdgcn_mfma_f32_16x16x32_f16(aq, xb[nt], aQ[nt], 0, 0, 0);
                aK[nt] = __builtin_amdgcn_mfma_f32_16x16x32_f16(ak, xb[nt], aK[nt], 0, 0, 0);
                aV[nt] = __builtin_amdgcn_mfma_f32_16x16x32_f16(av, xb[nt], aV[nt], 0, 0, 0);
            }
        }
        const int c0 = wid * 64 + pass * 16 + l4 * 4;
        f32x4 bqv = *(const f32x4*)(bq + c0);
        f32x4 bkv = *(const f32x4*)(bk + c0);
        f32x4 bvv = *(const f32x4*)(bv + c0);
        #pragma unroll
        for (int nt = 0; nt < 4; ++nt) {
            union { _Float16 h[4]; uint64_t q; } qp, kp, vp;
            #pragma unroll
            for (int ri = 0; ri < 4; ++ri) {
                qp.h[ri] = (_Float16)(aQ[nt][ri] + bqv[ri]);
                kp.h[ri] = (_Float16)(aK[nt][ri] + bkv[ri]);
                vp.h[ri] = (_Float16)(aV[nt][ri] + bvv[ri]);
            }
            qh[pass][nt] = qp.q;
            kh[pass][nt] = kp.q;
            vh[pass][nt] = vp.q;
        }
    }
    __syncthreads();

    #pragma unroll
    for (int pass = 0; pass < 4; ++pass) {
        const int c0 = wid * 64 + pass * 16 + l4 * 4;
        #pragma unroll
        for (int nt = 0; nt < 4; ++nt) {
            const int j = nt * 16 + l15;
            *(uint64_t*)(lds + Q_OFF + j * 512 + ((2 * c0) ^ SWZ(j))) = qh[pass][nt];
            *(uint64_t*)(lds + K_OFF + j * 512 + ((2 * c0) ^ SWZ(j))) = kh[pass][nt];
        }
    }
    __syncthreads();

    {
        const int i0 = wid * 16;
        f32x4 sa[4];
        #pragma unroll
        for (int jt = 0; jt < 4; ++jt) sa[jt] = (f32x4){0.f, 0.f, 0.f, 0.f};
        #pragma unroll
        for (int ks = 0; ks < 8; ++ks) {
            const int kb = ks * 64 + l4 * 16;
            const int iq = i0 + l15;
            half8 qa = *(const half8*)(lds + Q_OFF + iq * 512 + (kb ^ SWZ(iq)));
            #pragma unroll
            for (int jt = 0; jt < 4; ++jt) {
                const int jr = jt * 16 + l15;
                half8 kf = *(const half8*)(lds + K_OFF + jr * 512 + (kb ^ SWZ(jr)));
                sa[jt] = __builtin_amdgcn_mfma_f32_16x16x32_f16(qa, kf, sa[jt], 0, 0, 0);
            }
        }
        float msk[4];
        #pragma unroll
        for (int jt = 0; jt < 4; ++jt)
            msk[jt] = *(const float*)(lds + MSK_OFF + (jt * 16 + l15) * 4);
        #pragma unroll
        for (int ri = 0; ri < 4; ++ri) {
            float v[4];
            #pragma unroll
            for (int jt = 0; jt < 4; ++jt)
                v[jt] = (msk[jt] == 0.f) ? -1e30f : sa[jt][ri] * 0.0625f;
            float mx = fmaxf(fmaxf(v[0], v[1]), fmaxf(v[2], v[3]));
            mx = fmaxf(mx, __shfl_xor(mx, 1));
            mx = fmaxf(mx, __shfl_xor(mx, 2));
            mx = fmaxf(mx, __shfl_xor(mx, 4));
            mx = fmaxf(mx, __shfl_xor(mx, 8));
            float e[4], sum = 0.f;
            #pragma unroll
            for (int jt = 0; jt < 4; ++jt) { e[jt] = __expf(v[jt] - mx); sum += e[jt]; }
            sum += __shfl_xor(sum, 1);
            sum += __shfl_xor(sum, 2);
            sum += __shfl_xor(sum, 4);
            sum += __shfl_xor(sum, 8);
            const float inv = 1.f / sum;
            const int i = i0 + l4 * 4 + ri;
            #pragma unroll
            for (int jt = 0; jt < 4; ++jt) {
                const int j = jt * 16 + l15;
                *(_Float16*)(lds + P_OFF + i * 128 + ((2 * j) ^ SWZ(i))) =
                    (_Float16)(e[jt] * inv);
            }
        }
    }
    __syncthreads();

    #pragma unroll
    for (int pass = 0; pass < 4; ++pass) {
        const int c0 = wid * 64 + pass * 16 + l4 * 4;
        #pragma unroll
        for (int nt = 0; nt < 4; ++nt) {
            const int j = nt * 16 + l15;
            const uint64_t v64 = vh[pass][nt];
            #pragma unroll
            for (int ri = 0; ri < 4; ++ri) {
                const int c = c0 + ri;
                *(uint16_t*)(lds + V_OFF + c * 128 + ((2 * j) ^ SWZ(c))) =
                    (uint16_t)(v64 >> (16 * ri));
            }
        }
    }
    __syncthreads();

    {
        const int cb = wid * 64;
        f32x4 pv[4][4];
        #pragma unroll
        for (int m = 0; m < 4; ++m)
            #pragma unroll
            for (int q = 0; q < 4; ++q) pv[m][q] = (f32x4){0.f, 0.f, 0.f, 0.f};
        #pragma unroll
        for (int ks = 0; ks < 2; ++ks) {
            const int kb = ks * 64 + l4 * 16;
            half8 pb[4];
            #pragma unroll
            for (int nt = 0; nt < 4; ++nt) {
                const int i = nt * 16 + l15;
                pb[nt] = *(const half8*)(lds + P_OFF + i * 128 + (kb ^ SWZ(i)));
            }
            #pragma unroll
            for (int mt = 0; mt < 4; ++mt) {
                const int c = cb + mt * 16 + l15;
                half8 va = *(const half8*)(lds + V_OFF + c * 128 + (kb ^ SWZ(c)));
                #pragma unroll
                for (int nt = 0; nt < 4; ++nt)
                    pv[mt][nt] = __builtin_amdgcn_mfma_f32_16x16x32_f16(va, pb[nt], pv[mt][nt], 0, 0, 0);
            }
        }
        #pragma unroll
        for (int mt = 0; mt < 4; ++mt) {
            const int c0 = cb + mt * 16 + l4 * 4;
            #pragma unroll
            for (int nt = 0; nt < 4; ++nt) {
                const int j = nt * 16 + l15;
                union { _Float16 h[4]; uint64_t q; } hp;
                #pragma unroll
                for (int ri = 0; ri < 4; ++ri)
                    hp.h[ri] = (_Float16)fmaxf(pv[mt][nt][ri], 0.f);
                *(uint64_t*)(lds + H_OFF + j * 512 + ((2 * c0) ^ SWZ(j))) = hp.q;
            }
        }
    }
    __syncthreads();

    #pragma unroll
    for (int op = 0; op < 2; ++op) {
        const int mbo = wid * 128 + op * 64;
        const _Float16* wob = Wo + (size_t)(mbo + l15) * CRED + l4 * 8;
        f32x4 oa[4][4];
        #pragma unroll
        for (int m = 0; m < 4; ++m)
            #pragma unroll
            for (int q = 0; q < 4; ++q) oa[m][q] = (f32x4){0.f, 0.f, 0.f, 0.f};
        #pragma unroll 4
        for (int ks = 0; ks < 8; ++ks) {
            const int kb = ks * 64 + l4 * 16;
            half8 hb[4];
            #pragma unroll
            for (int nt = 0; nt < 4; ++nt) {
                const int i = nt * 16 + l15;
                hb[nt] = *(const half8*)(lds + H_OFF + i * 512 + (kb ^ SWZ(i)));
            }
            #pragma unroll
            for (int mt = 0; mt < 4; ++mt) {
                half8 wa = *(const half8*)(wob + mt * 16 * CRED + ks * 32);
                #pragma unroll
                for (int nt = 0; nt < 4; ++nt)
                    oa[mt][nt] = __builtin_amdgcn_mfma_f32_16x16x32_f16(wa, hb[nt], oa[mt][nt], 0, 0, 0);
            }
        }
        #pragma unroll
        for (int mt = 0; mt < 4; ++mt) {
            const int o0 = mbo + mt * 16 + l4 * 4;
            f32x4 bov = *(const f32x4*)(bo + o0);
            #pragma unroll
            for (int ri = 0; ri < 4; ++ri) {
                float* orow = out + ((size_t)b * CIN + (o0 + ri)) * LL + n * 64;
                #pragma unroll
                for (int nt = 0; nt < 4; ++nt)
                    orow[nt * 16 + l15] = oa[mt][nt][ri] + bov[ri];
            }
        }
    }
}

extern "C" void kernel_launch(void* const* d_in, const int* in_sizes, int n_in,
                              void* d_out, int out_size, void* d_ws, size_t ws_size,
                              hipStream_t stream) {
    const float* x1   = (const float*)d_in[0];
    // d_in[1] = x2 : unused by the reference
    const float* mask = (const float*)d_in[2];
    const float* Wq   = (const float*)d_in[3];
    const float* bq   = (const float*)d_in[4];
    const float* Wk   = (const float*)d_in[5];
    const float* bk   = (const float*)d_in[6];
    const float* Wv   = (const float*)d_in[7];
    const float* bv   = (const float*)d_in[8];
    const float* Wo   = (const float*)d_in[9];
    const float* bo   = (const float*)d_in[10];
    float* out = (float*)d_out;
    _Float16* wbuf = (_Float16*)d_ws;

    if (ws_size >= WS_NEED) {
        convert_weights_fm<<<2048, 256, 0, stream>>>(Wq, Wk, Wv, Wo, wbuf);
        _Float16* xfb = wbuf + XFH;
        for (int h = 0; h < 2; ++h) {
            x_transpose<<<2048, 256, 0, stream>>>(x1, xfb, 2 * h);
            qkv_v5<<<1536, 256, 0, stream>>>(wbuf, xfb, bq, bk, bv, wbuf, 2 * h);
        }
        attn_out<<<BB * NBLK, 256, LDS_B, stream>>>(mask, wbuf, bo, out);
    } else {
        convert_weights_rm<<<2048, 256, 0, stream>>>(Wq, Wk, Wv, Wo, wbuf);
        (void)hipFuncSetAttribute((const void*)att_fused,
                                  hipFuncAttributeMaxDynamicSharedMemorySize, LDS_BYTES);
        att_fused<<<BB * NBLK, 256, LDS_BYTES, stream>>>(x1, mask, wbuf, bq, bk, bv, bo, out);
    }
}